// Round 1
// baseline (232.376 us; speedup 1.0000x reference)
//
#include <hip/hip_runtime.h>

// Problem shape (fixed by reference setup_inputs)
#define BATCH 256
#define NJ    17
#define HW    6912          // 96*72, contiguous per (b,j) slab
#define NF4   1728          // HW / 4 float4s per slab = 256*6 + 192
#define NSLAB (BATCH * NJ)  // 4352

typedef float f4 __attribute__((ext_vector_type(4)));

// R5: staged-drain streaming.
// History: cached loads = 90us (L2-allocate limited); plain nt = 65us;
// full bypass sc0+sc1+nt = no change in total (233.0 -> 232.2, noise).
// Theory: 65us = 3.7 TB/s because (a) every wave issues 12 loads then parks
// at vmcnt(0) -> correlated compute/retire gaps leave HBM idle, and
// (b) sc1 system-scope forfeits L3 hits on the freshly-restored inputs
// (240.6 MB <= 256 MB Infinity Cache).
// This round: nt-only loads (L3-servable), uniform 14-deep pipeline
// (clamped tail, masked FMA), staged vmcnt drains (12,10,...,0) with FMAs
// interleaved, dual acc chains.
__global__ __launch_bounds__(256) void ohkm_slab_kernel(
    const float* __restrict__ outp,
    const float* __restrict__ tgtp,
    const float* __restrict__ twp,
    float* __restrict__ partial /* [NJ][BATCH] */) {
  const int slab = blockIdx.x;          // slab = b*NJ + j
  const int tid = threadIdx.x;
  const f4* o4 = (const f4*)(outp + (size_t)slab * HW);
  const f4* t4 = (const f4*)(tgtp + (size_t)slab * HW);

  // Hoist the (wave-uniform) weight load so its latency hides under the
  // streaming loads instead of sitting on the epilogue critical path.
  const float w = twp[slab];

  // Tail chunk: NF4 - 6*256 = 192. Clamp the index so ALL lanes issue a
  // 7th pair (uniform 14-deep pipeline, uniform vmcnt constants for every
  // wave); lanes >= 192 re-read an earlier element and mask its FMA.
  const int tidx6 = 6 * 256 + (tid < 192 ? tid : tid - 192);
  const float tmask = (tid < 192) ? 1.f : 0.f;

  f4 o[7], t[7];
  // 14 loads issued back-to-back, order o0,t0,o1,t1,...,o6,t6.
  // nt = L2 no-allocate but L3-servable; volatile keeps issue order so the
  // staged vmcnt immediates below are exact.
#pragma unroll
  for (int it = 0; it < 6; ++it) {
    asm volatile("global_load_dwordx4 %0, %1, off nt"
                 : "=v"(o[it]) : "v"(o4 + tid + it * 256));
    asm volatile("global_load_dwordx4 %0, %1, off nt"
                 : "=v"(t[it]) : "v"(t4 + tid + it * 256));
  }
  asm volatile("global_load_dwordx4 %0, %1, off nt"
               : "=v"(o[6]) : "v"(o4 + tidx6));
  asm volatile("global_load_dwordx4 %0, %1, off nt"
               : "=v"(t[6]) : "v"(t4 + tidx6));

  // Staged drain: wait only for the oldest pair, FMA it, repeat. Waves wake
  // early and their compute overlaps the remaining in-flight loads; no
  // correlated full-drain stall. Each wait ties exactly the pair it guards
  // ("+v" makes the wait a def -> uses can't be hoisted above it; volatile
  // asms keep mutual program order vs the loads).
  float acc0 = 0.f, acc1 = 0.f;
#define DRAIN2(N, A, B) \
  asm volatile("s_waitcnt vmcnt(" #N ")" : "+v"(A), "+v"(B))
#define ACCUM(I)                     \
  do {                               \
    f4 d = o[I] - t[I];              \
    acc0 = fmaf(d.x, d.x, acc0);     \
    acc1 = fmaf(d.y, d.y, acc1);     \
    acc0 = fmaf(d.z, d.z, acc0);     \
    acc1 = fmaf(d.w, d.w, acc1);     \
  } while (0)

  DRAIN2(12, o[0], t[0]); ACCUM(0);
  DRAIN2(10, o[1], t[1]); ACCUM(1);
  DRAIN2(8,  o[2], t[2]); ACCUM(2);
  DRAIN2(6,  o[3], t[3]); ACCUM(3);
  DRAIN2(4,  o[4], t[4]); ACCUM(4);
  DRAIN2(2,  o[5], t[5]); ACCUM(5);
  DRAIN2(0,  o[6], t[6]);
  {
    f4 d = o[6] - t[6];
    d.x *= tmask; d.y *= tmask; d.z *= tmask; d.w *= tmask;
    acc0 = fmaf(d.x, d.x, acc0);
    acc1 = fmaf(d.y, d.y, acc1);
    acc0 = fmaf(d.z, d.z, acc0);
    acc1 = fmaf(d.w, d.w, acc1);
  }
#undef DRAIN2
#undef ACCUM

  float acc = acc0 + acc1;
  // wave (64-lane) reduction
  for (int off = 32; off; off >>= 1) acc += __shfl_down(acc, off, 64);

  __shared__ float sred[4];
  const int lane = tid & 63;
  const int wv   = tid >> 6;
  if (lane == 0) sred[wv] = acc;
  __syncthreads();

  if (tid == 0) {
    const float v = (sred[0] + sred[1] + sred[2] + sred[3]) * (w * w);
    const int j = slab % NJ;
    const int b = slab / NJ;
    partial[j * BATCH + b] = v;
  }
}

// Kernel 2: single block, latency-optimized. 4 waves process joints in
// parallel (wave w -> joints w, w+4, ...). Each lane loads a float4 of 4
// batch-partials (coalesced, issued upfront), independent shfl chains give
// ILP. One barrier, then thread 0 does the 17-way top-k.
__global__ __launch_bounds__(256) void ohkm_finish_kernel(
    const float* __restrict__ partial /* [NJ][BATCH] */,
    const int* __restrict__ topk_p,
    float* __restrict__ out) {
  __shared__ float losses[NJ];
  const int tid  = threadIdx.x;
  const int lane = tid & 63;
  const int wv   = tid >> 6;
  const float inv_n = 1.0f / (float)((size_t)BATCH * HW);

  // wave w handles joints w, w+4, w+8, ... (wave 0 gets 5, others 4)
  f4 v4[5];
  int nj = 0;
#pragma unroll
  for (int j = wv, s = 0; s < 5; ++s, j += 4) {
    if (j < NJ) {
      v4[s] = *(const f4*)(partial + j * BATCH + lane * 4);
      nj = s + 1;
    }
  }

  float sums[5];
#pragma unroll
  for (int s = 0; s < 5; ++s) {
    if (s < nj) {
      f4 v = v4[s];
      sums[s] = (v.x + v.y) + (v.z + v.w);
    } else {
      sums[s] = 0.f;
    }
  }

  // independent 6-level shfl reductions (compiler interleaves -> ILP)
#pragma unroll
  for (int off = 32; off; off >>= 1) {
#pragma unroll
    for (int s = 0; s < 5; ++s) {
      sums[s] += __shfl_down(sums[s], off, 64);
    }
  }

  if (lane == 0) {
#pragma unroll
    for (int s = 0; s < 5; ++s) {
      const int j = wv + 4 * s;
      if (j < NJ) losses[j] = sums[s] * inv_n;
    }
  }
  __syncthreads();

  if (tid == 0) {
    int k = *topk_p;
    if (k < 1) k = 1;
    if (k > NJ) k = NJ;
    float vals[NJ];
#pragma unroll
    for (int j = 0; j < NJ; ++j) vals[j] = losses[j];
    float sum = 0.f;
    for (int i = 0; i < k; ++i) {
      int best = 0;
      float bv = -3.0e38f;
      for (int j = 0; j < NJ; ++j) {
        if (vals[j] > bv) { bv = vals[j]; best = j; }
      }
      sum += bv;
      vals[best] = -3.0e38f;
    }
    out[0] = sum / (float)k;
  }
}

extern "C" void kernel_launch(void* const* d_in, const int* in_sizes, int n_in,
                              void* d_out, int out_size, void* d_ws, size_t ws_size,
                              hipStream_t stream) {
  const float* outp = (const float*)d_in[0];
  const float* tgtp = (const float*)d_in[1];
  const float* twp  = (const float*)d_in[2];
  const int*   tkp  = (const int*)d_in[3];
  float* partial = (float*)d_ws;   // NJ*BATCH floats = 17408 bytes
  float* outv    = (float*)d_out;

  ohkm_slab_kernel<<<NSLAB, 256, 0, stream>>>(outp, tgtp, twp, partial);
  ohkm_finish_kernel<<<1, 256, 0, stream>>>(partial, tkp, outv);
}